// Round 15
// baseline (129.570 us; speedup 1.0000x reference)
//
#include <hip/hip_runtime.h>

#define NG 256
#define NG2 (NG*NG)
#define NREP 8                      // counter replicas (contention spreading)

constexpr float DX      = 1.0f / 256.0f;
constexpr float INV_DX  = 256.0f;
constexpr float DT      = 2e-5f;
constexpr float P_VOL   = (1.0f/512.0f) * (1.0f/512.0f);
constexpr float P_MASS  = P_VOL;           // rho = 1
constexpr float MU_0    = 1000.0f / (2.0f * 1.2f);            // E/(2(1+nu))
constexpr float LAM_0   = 1000.0f * 0.2f / (1.2f * 0.6f);     // E nu/((1+nu)(1-2nu))
constexpr float GRAV    = 50.0f;

__device__ __forceinline__ int bin_of(float px, float py) {
    int bx = (int)floorf(px * INV_DX - 0.5f);
    int by = (int)floorf(py * INV_DX - 0.5f);
    bx = min(max(bx, 0), NG - 1);
    by = min(max(by, 0), NG - 1);
    return (bx << 8) | by;
}

// quadratic B-spline weight as a function of (node - particle) distance in cells
__device__ __forceinline__ float bw(float t) {
    float at = fabsf(t);
    float a  = fmaxf(1.5f - at, 0.0f);
    float w1 = 0.75f - t * t;
    float w2 = 0.5f * a * a;
    return (at < 0.5f) ? w1 : w2;
}

// ---------------- binning (replica-split counters) ----------------

// counts rep-major: counts8[rep*NG2 + bin] -> a bin's replicas in 8 cache lines.
// rank fits in uint8: per-(bin,rep) count ~ Poisson(2), max << 255.
__global__ __launch_bounds__(256) void binrank_kernel(
    const float* __restrict__ x, int* __restrict__ counts8,
    unsigned char* __restrict__ rank, int n)
{
    int i = blockIdx.x * blockDim.x + threadIdx.x;
    if (i >= n) return;
    float2 p = ((const float2*)x)[i];
    int b = bin_of(p.x, p.y);
    int rep = (i >> 8) & (NREP - 1);
    rank[i] = (unsigned char)atomicAdd(&counts8[rep * NG2 + b], 1);
}

// Per bin: pack intra-bin per-rep prefix offsets (uint8 x8, bin count << 255)
// into a uint2, and block-scan the bin totals. 256 blocks x 256 threads.
__global__ __launch_bounds__(256) void scan1_kernel(
    const int* __restrict__ counts8, uint2* __restrict__ offs8,
    int* __restrict__ starts, int* __restrict__ bsum)
{
    __shared__ int tmp[256];
    int t = threadIdx.x, blk = blockIdx.x;
    int b = blk * 256 + t;

    int c0 = counts8[0*NG2 + b], c1 = counts8[1*NG2 + b];
    int c2 = counts8[2*NG2 + b], c3 = counts8[3*NG2 + b];
    int c4 = counts8[4*NG2 + b], c5 = counts8[5*NG2 + b];
    int c6 = counts8[6*NG2 + b], c7 = counts8[7*NG2 + b];
    int o1 = c0, o2 = o1+c1, o3 = o2+c2, o4 = o3+c3;
    int o5 = o4+c4, o6 = o5+c5, o7 = o6+c6;
    int total = o7 + c7;
    uint2 packed;
    packed.x = (unsigned)(o1 << 8) | ((unsigned)o2 << 16) | ((unsigned)o3 << 24);
    packed.y = (unsigned)o4 | ((unsigned)o5 << 8) | ((unsigned)o6 << 16) | ((unsigned)o7 << 24);
    offs8[b] = packed;

    tmp[t] = total;
    __syncthreads();
    #pragma unroll
    for (int off = 1; off < 256; off <<= 1) {
        int add = (t >= off) ? tmp[t - off] : 0;
        __syncthreads();
        tmp[t] += add;
        __syncthreads();
    }
    starts[b] = tmp[t] - total;            // exclusive within block
    if (t == 255) bsum[blk] = tmp[255];    // block total
}

__global__ __launch_bounds__(256) void scan2_kernel(int* __restrict__ bsum)
{
    __shared__ int tmp[256];
    int t = threadIdx.x;
    int v = bsum[t];
    tmp[t] = v;
    __syncthreads();
    #pragma unroll
    for (int off = 1; off < 256; off <<= 1) {
        int add = (t >= off) ? tmp[t - off] : 0;
        __syncthreads();
        tmp[t] += add;
        __syncthreads();
    }
    bsum[t] = tmp[t] - v;                  // exclusive
}

__global__ __launch_bounds__(256) void scan3_kernel(
    int* __restrict__ starts, const int* __restrict__ bsum, int n)
{
    int i = blockIdx.x * blockDim.x + threadIdx.x;
    if (i < NG2) starts[i] += bsum[i >> 8];
    if (i == 0) starts[NG2] = n;
}

// ---------------- particle update + sorted interleaved record scatter ----------------

__global__ __launch_bounds__(256) void compute_scatter_kernel(
    const float* __restrict__ x, const float* __restrict__ v,
    const float* __restrict__ C, const float* __restrict__ F,
    const int* __restrict__ mat, const float* __restrict__ Jp,
    const int* __restrict__ starts, const uint2* __restrict__ offs8,
    const unsigned char* __restrict__ rank,
    float4* __restrict__ srec,          // interleaved: srec[2k] = pos/b, srec[2k+1] = A
    float4* __restrict__ F_out4, float* __restrict__ mat_out, float* __restrict__ Jp_out,
    int n)
{
    int i = blockIdx.x * blockDim.x + threadIdx.x;
    if (i >= n) return;

    float2 xp = ((const float2*)x)[i];
    float px = xp.x, py = xp.y;

    // ---- scatter-address chain issued EARLY: its L2 latency hides under the
    // SVD/stress VALU chain below ----
    int bin = bin_of(px, py);
    int rep = (i >> 8) & (NREP - 1);
    uint2 o8 = offs8[bin];
    int sb = starts[bin];
    int rk = (int)rank[i];

    float2 vp = ((const float2*)v)[i];
    float4 Cp = ((const float4*)C)[i];
    float4 Fp = ((const float4*)F)[i];
    int    m  = mat[i];
    float  jp = Jp[i];

    float C00 = Cp.x, C01 = Cp.y, C10 = Cp.z, C11 = Cp.w;
    float a = Fp.x, b = Fp.y, c = Fp.z, d = Fp.w;

    // F += dt * C @ F
    float na = a + DT*(C00*a + C01*c);
    float nb = b + DT*(C00*b + C01*d);
    float nc = c + DT*(C10*a + C11*c);
    float nd = d + DT*(C10*b + C11*d);
    a = na; b = nb; c = nc; d = nd;

    float h = expf(10.0f * (1.0f - jp));
    if (m == 1) h = 0.3f;
    float mu  = (m == 0) ? 0.0f : MU_0 * h;
    float lam = LAM_0 * h;

    // closed-form 2x2 SVD via eigendecomposition of A^T A
    float S00 = a*a + c*c, S01 = a*b + c*d, S11 = b*b + d*d;
    float mh = 0.5f*(S00 + S11), dh = 0.5f*(S00 - S11);
    float delta = sqrtf(dh*dh + S01*S01);
    float sig1 = sqrtf(fmaxf(mh + delta, 0.0f));
    float sig2 = sqrtf(fmaxf(mh - delta, 0.0f));
    float e0, e1;
    if (dh >= 0.0f) { e0 = delta + dh; e1 = S01; }
    else            { e0 = S01;        e1 = delta - dh; }
    float elen = sqrtf(e0*e0 + e1*e1);
    float vc, vs;
    if (elen > 1e-30f) { float il = 1.0f/elen; vc = e0*il; vs = e1*il; }
    else               { vc = 1.0f; vs = 0.0f; }
    float inv1 = 1.0f / fmaxf(sig1, 1e-30f);
    float inv2 = 1.0f / fmaxf(sig2, 1e-30f);
    float u1x = ( a*vc + b*vs) * inv1, u1y = ( c*vc + d*vs) * inv1;
    float u2x = (-a*vs + b*vc) * inv2, u2y = (-c*vs + d*vc) * inv2;

    if (m == 2) {   // snow plasticity
        float c1 = fminf(fmaxf(sig1, 1.0f - 2.5e-2f), 1.0f + 4.5e-3f);
        float c2 = fminf(fmaxf(sig2, 1.0f - 2.5e-2f), 1.0f + 4.5e-3f);
        jp = jp * (sig1 / c1) * (sig2 / c2);
        sig1 = c1; sig2 = c2;
    }
    float J = sig1 * sig2;

    if (m == 0) {              // fluid: F = sqrt(J) I
        float s = sqrtf(J);
        a = s; b = 0.0f; c = 0.0f; d = s;
    } else if (m == 2) {       // snow: F = U diag(sig) Vh
        a = sig1*u1x*vc - sig2*u2x*vs;
        b = sig1*u1x*vs + sig2*u2x*vc;
        c = sig1*u1y*vc - sig2*u2y*vs;
        d = sig1*u1y*vs + sig2*u2y*vc;
    }
    float R00 = u1x*vc - u2x*vs, R01 = u1x*vs + u2x*vc;
    float R10 = u1y*vc - u2y*vs, R11 = u1y*vs + u2y*vc;

    float k2mu = 2.0f * mu;
    float fr00 = a - R00, fr01 = b - R01, fr10 = c - R10, fr11 = d - R11;
    float ljj  = lam * J * (J - 1.0f);
    float st00 = k2mu*(fr00*a + fr01*b) + ljj;
    float st01 = k2mu*(fr00*c + fr01*d);
    float st10 = k2mu*(fr10*a + fr11*b);
    float st11 = k2mu*(fr10*c + fr11*d) + ljj;
    const float coef = -DT * P_VOL * 4.0f * INV_DX * INV_DX;
    float A00 = coef*st00 + P_MASS*C00;
    float A01 = coef*st01 + P_MASS*C01;
    float A10 = coef*st10 + P_MASS*C10;
    float A11 = coef*st11 + P_MASS*C11;

    float bx_ = P_MASS*vp.x - (A00*px + A01*py);
    float by_ = P_MASS*vp.y - (A10*px + A11*py);

    // interleaved 32B record at sorted slot: both halves hit the same 64B line
    unsigned offv = (rep < 4 ? (o8.x >> (8*rep)) : (o8.y >> (8*(rep-4)))) & 255u;
    int sidx = sb + (int)offv + rk;
    srec[2*sidx]     = make_float4(px * INV_DX, py * INV_DX, bx_, by_);
    srec[2*sidx + 1] = make_float4(A00, A01, A10, A11);

    F_out4[i]  = make_float4(a, b, c, d);
    mat_out[i] = (float)m;
    Jp_out[i]  = jp;
}

// 16 threads per grid cell: gather from 3 contiguous sorted ranges (strided by
// slice, 2x unrolled so two record-pairs are in flight), shuffle-reduce within
// the 16-lane group, fuse grid ops. XCD-swizzled blocks keep rows L2-local.
__global__ __launch_bounds__(256) void gather_grid_kernel(
    const float4* __restrict__ srec, const int* __restrict__ starts,
    float2* __restrict__ gv)
{
    // bijective XCD swizzle: nwg = NG2*16/256 = 4096, 4096 % 8 == 0
    int bid  = blockIdx.x;
    int swz  = (bid & 7) * (4096 / 8) + (bid >> 3);
    int gtid  = swz * 256 + threadIdx.x;
    int cell  = gtid >> 4;
    int slice = gtid & 15;
    int gi = cell >> 8, gj = cell & (NG - 1);

    float fgi = (float)gi, fgj = (float)gj;
    float posx = fgi * DX, posy = fgj * DX;
    float msum = 0.0f, mvx = 0.0f, mvy = 0.0f;

    int j0 = max(gj - 2, 0);

    // prefetch all 6 range bounds (up to 3 bin rows)
    int sArr[3], eArr[3];
    #pragma unroll
    for (int t3 = 0; t3 < 3; ++t3) {
        int bi = gi - 2 + t3;
        bool valid = (bi >= 0);
        int row = (valid ? bi : 0) << 8;
        sArr[t3] = valid ? starts[row + j0] : 0;
        eArr[t3] = valid ? starts[row + gj + 1] : 0;
    }

    #pragma unroll
    for (int t3 = 0; t3 < 3; ++t3) {
        int s = sArr[t3], e = eArr[t3];
        for (int k = s + slice; k < e; k += 32) {
            float4 r0 = srec[2*k];
            float4 r1 = srec[2*k + 1];
            int k2 = k + 16;
            bool sec = (k2 < e);
            float4 q0, q1;
            if (sec) { q0 = srec[2*k2]; q1 = srec[2*k2 + 1]; }
            float w = bw(r0.x - fgi) * bw(r0.y - fgj);
            msum += w;
            mvx  += w * (r0.z + r1.x * posx + r1.y * posy);
            mvy  += w * (r0.w + r1.z * posx + r1.w * posy);
            if (sec) {
                float w2 = bw(q0.x - fgi) * bw(q0.y - fgj);
                msum += w2;
                mvx  += w2 * (q0.z + q1.x * posx + q1.y * posy);
                mvy  += w2 * (q0.w + q1.z * posx + q1.w * posy);
            }
        }
    }

    // reduce across the 16 slices (lanes differing in bits 0..3 of lane id)
    #pragma unroll
    for (int off = 1; off < 16; off <<= 1) {
        msum += __shfl_xor(msum, off);
        mvx  += __shfl_xor(mvx,  off);
        mvy  += __shfl_xor(mvy,  off);
    }

    if (slice == 0) {
        float mass = msum * P_MASS;
        float vx = mvx, vy = mvy;
        if (mass > 0.0f) {
            float im = 1.0f / fmaxf(mass, 1e-12f);
            vx *= im; vy *= im;
        }
        vy -= DT * GRAV;
        if (gi < 3)      vx = fmaxf(vx, 0.0f);
        if (gi >= NG-2)  vx = fminf(vx, 0.0f);
        if (gj < 3)      vy = fmaxf(vy, 0.0f);
        if (gj >= NG-2)  vy = fminf(vy, 0.0f);
        gv[cell] = make_float2(vx, vy);
    }
}

__global__ __launch_bounds__(256) void g2p_kernel(
    const float* __restrict__ x, const float2* __restrict__ gv,
    float* __restrict__ x_out, float* __restrict__ v_out, float* __restrict__ C_out,
    int n)
{
    int i = blockIdx.x * blockDim.x + threadIdx.x;
    if (i >= n) return;

    float2 xp = ((const float2*)x)[i];
    float px = xp.x, py = xp.y;
    float bxf = floorf(px * INV_DX - 0.5f), byf = floorf(py * INV_DX - 0.5f);
    float fx = px * INV_DX - bxf, fy = py * INV_DX - byf;
    float wxs[3] = { 0.5f*(1.5f-fx)*(1.5f-fx), 0.75f-(fx-1.0f)*(fx-1.0f), 0.5f*(fx-0.5f)*(fx-0.5f) };
    float wys[3] = { 0.5f*(1.5f-fy)*(1.5f-fy), 0.75f-(fy-1.0f)*(fy-1.0f), 0.5f*(fy-0.5f)*(fy-0.5f) };
    int bix = (int)bxf, biy = (int)byf;

    float nvx = 0.0f, nvy = 0.0f;
    float c00 = 0.0f, c01 = 0.0f, c10 = 0.0f, c11 = 0.0f;
    #pragma unroll
    for (int ii = 0; ii < 3; ++ii) {
        float posx = (bxf + (float)ii) * DX;
        int rowbase = (bix + ii) * NG + biy;
        #pragma unroll
        for (int jj = 0; jj < 3; ++jj) {
            float w = wxs[ii] * wys[jj];
            float posy = (byf + (float)jj) * DX;
            float2 g = gv[rowbase + jj];
            nvx += w * g.x; nvy += w * g.y;
            c00 += w * g.x * posx; c01 += w * g.x * posy;
            c10 += w * g.y * posx; c11 += w * g.y * posy;
        }
    }
    const float K = 4.0f * INV_DX * INV_DX;
    c00 = (c00 - nvx * px) * K; c01 = (c01 - nvx * py) * K;
    c10 = (c10 - nvy * px) * K; c11 = (c11 - nvy * py) * K;

    ((float2*)x_out)[i] = make_float2(px + DT * nvx, py + DT * nvy);
    ((float2*)v_out)[i] = make_float2(nvx, nvy);
    ((float4*)C_out)[i] = make_float4(c00, c01, c10, c11);
}

extern "C" void kernel_launch(void* const* d_in, const int* in_sizes, int n_in,
                              void* d_out, int out_size, void* d_ws, size_t ws_size,
                              hipStream_t stream) {
    const float* x   = (const float*)d_in[0];
    const float* v   = (const float*)d_in[1];
    const float* C   = (const float*)d_in[2];
    const float* F   = (const float*)d_in[3];
    const int*   mat = (const int*)d_in[4];
    const float* Jp  = (const float*)d_in[5];

    int n = in_sizes[0] / 2;

    float* out     = (float*)d_out;
    float* x_out   = out;
    float* v_out   = out + (size_t)2*n;
    float* C_out   = out + (size_t)4*n;
    float* F_out   = out + (size_t)8*n;
    float* mat_out = out + (size_t)12*n;
    float* Jp_out  = out + (size_t)13*n;

    // srec (32 MB) lives in d_out[0 .. 8n) floats (x/v/C regions), overwritten
    // by g2p at the very end. Fully written by compute_scatter each call.
    float4* srec = (float4*)out;

    int blocks = (n + 255) / 256;

    // workspace layout (~4.5 MB)
    char* ws = (char*)d_ws;
    size_t off = 0;
    int*   counts8 = (int*)(ws + off);  off += (size_t)NG2 * NREP * 4;
    int*   starts  = (int*)(ws + off);  off += (size_t)(NG2 + 1) * 4;
    uint2* offs8   = (uint2*)(ws + off); off += (size_t)NG2 * 8;
    int*   bsum    = (int*)(ws + off);  off += 256 * 4;
    unsigned char* rank = (unsigned char*)(ws + off); off += (size_t)n;
    off = (off + 63) & ~(size_t)63;
    float2* gv     = (float2*)(ws + off); off += (size_t)NG2 * 8;

    hipMemsetAsync(counts8, 0, (size_t)NG2 * NREP * 4, stream);
    binrank_kernel<<<blocks, 256, 0, stream>>>(x, counts8, rank, n);
    scan1_kernel<<<NG2/256, 256, 0, stream>>>(counts8, offs8, starts, bsum);
    scan2_kernel<<<1, 256, 0, stream>>>(bsum);
    scan3_kernel<<<NG2/256, 256, 0, stream>>>(starts, bsum, n);
    compute_scatter_kernel<<<blocks, 256, 0, stream>>>(x, v, C, F, mat, Jp,
                                                       starts, offs8, rank, srec,
                                                       (float4*)F_out, mat_out, Jp_out, n);
    gather_grid_kernel<<<(NG2*16)/256, 256, 0, stream>>>(srec, starts, gv);
    g2p_kernel<<<blocks, 256, 0, stream>>>(x, gv, x_out, v_out, C_out, n);
}

// Round 17
// 128.269 us; speedup vs baseline: 1.0101x; 1.0101x over previous
//
#include <hip/hip_runtime.h>
#include <hip/hip_fp16.h>

#define NG 256
#define NG2 (NG*NG)
#define NREP 8                      // counter replicas (contention spreading)

constexpr float DX      = 1.0f / 256.0f;
constexpr float INV_DX  = 256.0f;
constexpr float DT      = 2e-5f;
constexpr float P_VOL   = (1.0f/512.0f) * (1.0f/512.0f);
constexpr float P_MASS  = P_VOL;           // rho = 1
constexpr float MU_0    = 1000.0f / (2.0f * 1.2f);            // E/(2(1+nu))
constexpr float LAM_0   = 1000.0f * 0.2f / (1.2f * 0.6f);     // E nu/((1+nu)(1-2nu))
constexpr float GRAV    = 50.0f;
constexpr float KA      = -DT * 4.0f * INV_DX * INV_DX;       // coef / P_MASS
constexpr float MINMS   = 1e-12f / P_MASS;                    // mass floor in msum units

__device__ __forceinline__ int bin_of(float px, float py) {
    int bx = (int)floorf(px * INV_DX - 0.5f);
    int by = (int)floorf(py * INV_DX - 0.5f);
    bx = min(max(bx, 0), NG - 1);
    by = min(max(by, 0), NG - 1);
    return (bx << 8) | by;
}

// quadratic B-spline weight as a function of (node - particle) distance in cells
__device__ __forceinline__ float bw(float t) {
    float at = fabsf(t);
    float a  = fmaxf(1.5f - at, 0.0f);
    float w1 = 0.75f - t * t;
    float w2 = 0.5f * a * a;
    return (at < 0.5f) ? w1 : w2;
}

__device__ __forceinline__ unsigned pack_h2(float a, float b) {
    union { __half2 h; unsigned u; } cv;
    cv.h = __floats2half2_rn(a, b);
    return cv.u;
}
__device__ __forceinline__ float2 unpack_h2(unsigned u) {
    union { __half2 h; unsigned u; } cv;
    cv.u = u;
    return __half22float2(cv.h);
}

// ---------------- binning (replica-split counters) ----------------

__global__ __launch_bounds__(256) void binrank_kernel(
    const float* __restrict__ x, int* __restrict__ counts8,
    unsigned char* __restrict__ rank, int n)
{
    int i = blockIdx.x * blockDim.x + threadIdx.x;
    if (i >= n) return;
    float2 p = ((const float2*)x)[i];
    int b = bin_of(p.x, p.y);
    int rep = (i >> 8) & (NREP - 1);
    rank[i] = (unsigned char)atomicAdd(&counts8[rep * NG2 + b], 1);
}

__global__ __launch_bounds__(256) void scan1_kernel(
    const int* __restrict__ counts8, uint2* __restrict__ offs8,
    int* __restrict__ starts, int* __restrict__ bsum)
{
    __shared__ int tmp[256];
    int t = threadIdx.x, blk = blockIdx.x;
    int b = blk * 256 + t;

    int c0 = counts8[0*NG2 + b], c1 = counts8[1*NG2 + b];
    int c2 = counts8[2*NG2 + b], c3 = counts8[3*NG2 + b];
    int c4 = counts8[4*NG2 + b], c5 = counts8[5*NG2 + b];
    int c6 = counts8[6*NG2 + b], c7 = counts8[7*NG2 + b];
    int o1 = c0, o2 = o1+c1, o3 = o2+c2, o4 = o3+c3;
    int o5 = o4+c4, o6 = o5+c5, o7 = o6+c6;
    int total = o7 + c7;
    uint2 packed;
    packed.x = (unsigned)(o1 << 8) | ((unsigned)o2 << 16) | ((unsigned)o3 << 24);
    packed.y = (unsigned)o4 | ((unsigned)o5 << 8) | ((unsigned)o6 << 16) | ((unsigned)o7 << 24);
    offs8[b] = packed;

    tmp[t] = total;
    __syncthreads();
    #pragma unroll
    for (int off = 1; off < 256; off <<= 1) {
        int add = (t >= off) ? tmp[t - off] : 0;
        __syncthreads();
        tmp[t] += add;
        __syncthreads();
    }
    starts[b] = tmp[t] - total;
    if (t == 255) bsum[blk] = tmp[255];
}

__global__ __launch_bounds__(256) void scan2_kernel(int* __restrict__ bsum)
{
    __shared__ int tmp[256];
    int t = threadIdx.x;
    int v = bsum[t];
    tmp[t] = v;
    __syncthreads();
    #pragma unroll
    for (int off = 1; off < 256; off <<= 1) {
        int add = (t >= off) ? tmp[t - off] : 0;
        __syncthreads();
        tmp[t] += add;
        __syncthreads();
    }
    bsum[t] = tmp[t] - v;
}

__global__ __launch_bounds__(256) void scan3_kernel(
    int* __restrict__ starts, const int* __restrict__ bsum, int n)
{
    int i = blockIdx.x * blockDim.x + threadIdx.x;
    if (i < NG2) starts[i] += bsum[i >> 8];
    if (i == 0) starts[NG2] = n;
}

// ---------------- particle update + compact 16B sorted record scatter ----------------
// record uint4: x = fx|fy (u16 frac within bin), y = half2(b''), z/w = half2 rows
// of A' = A/P_MASS, with b'' = v + A'*(bin_center - x), center = x - DX*frac.

__global__ __launch_bounds__(256) void compute_scatter_kernel(
    const float* __restrict__ x, const float* __restrict__ v,
    const float* __restrict__ C, const float* __restrict__ F,
    const int* __restrict__ mat, const float* __restrict__ Jp,
    const int* __restrict__ starts, const uint2* __restrict__ offs8,
    const unsigned char* __restrict__ rank,
    uint4* __restrict__ srec,
    float4* __restrict__ F_out4, float* __restrict__ mat_out, float* __restrict__ Jp_out,
    int n)
{
    int i = blockIdx.x * blockDim.x + threadIdx.x;
    if (i >= n) return;

    float2 xp = ((const float2*)x)[i];
    float px = xp.x, py = xp.y;

    // scatter-address chain early: L2 latency hides under the SVD chain
    int bin = bin_of(px, py);
    int rep = (i >> 8) & (NREP - 1);
    uint2 o8 = offs8[bin];
    int sb = starts[bin];
    int rk = (int)rank[i];

    float2 vp = ((const float2*)v)[i];
    float4 Cp = ((const float4*)C)[i];
    float4 Fp = ((const float4*)F)[i];
    int    m  = mat[i];
    float  jp = Jp[i];

    float C00 = Cp.x, C01 = Cp.y, C10 = Cp.z, C11 = Cp.w;
    float a = Fp.x, b = Fp.y, c = Fp.z, d = Fp.w;

    // F += dt * C @ F
    float na = a + DT*(C00*a + C01*c);
    float nb = b + DT*(C00*b + C01*d);
    float nc = c + DT*(C10*a + C11*c);
    float nd = d + DT*(C10*b + C11*d);
    a = na; b = nb; c = nc; d = nd;

    float h = expf(10.0f * (1.0f - jp));
    if (m == 1) h = 0.3f;
    float mu  = (m == 0) ? 0.0f : MU_0 * h;
    float lam = LAM_0 * h;

    // closed-form 2x2 SVD via eigendecomposition of A^T A
    float S00 = a*a + c*c, S01 = a*b + c*d, S11 = b*b + d*d;
    float mh = 0.5f*(S00 + S11), dh = 0.5f*(S00 - S11);
    float delta = sqrtf(dh*dh + S01*S01);
    float sig1 = sqrtf(fmaxf(mh + delta, 0.0f));
    float sig2 = sqrtf(fmaxf(mh - delta, 0.0f));
    float e0, e1;
    if (dh >= 0.0f) { e0 = delta + dh; e1 = S01; }
    else            { e0 = S01;        e1 = delta - dh; }
    float elen = sqrtf(e0*e0 + e1*e1);
    float vc, vs;
    if (elen > 1e-30f) { float il = 1.0f/elen; vc = e0*il; vs = e1*il; }
    else               { vc = 1.0f; vs = 0.0f; }
    float inv1 = 1.0f / fmaxf(sig1, 1e-30f);
    float inv2 = 1.0f / fmaxf(sig2, 1e-30f);
    float u1x = ( a*vc + b*vs) * inv1, u1y = ( c*vc + d*vs) * inv1;
    float u2x = (-a*vs + b*vc) * inv2, u2y = (-c*vs + d*vc) * inv2;

    if (m == 2) {   // snow plasticity
        float c1 = fminf(fmaxf(sig1, 1.0f - 2.5e-2f), 1.0f + 4.5e-3f);
        float c2 = fminf(fmaxf(sig2, 1.0f - 2.5e-2f), 1.0f + 4.5e-3f);
        jp = jp * (sig1 / c1) * (sig2 / c2);
        sig1 = c1; sig2 = c2;
    }
    float J = sig1 * sig2;

    if (m == 0) {              // fluid: F = sqrt(J) I
        float s = sqrtf(J);
        a = s; b = 0.0f; c = 0.0f; d = s;
    } else if (m == 2) {       // snow: F = U diag(sig) Vh
        a = sig1*u1x*vc - sig2*u2x*vs;
        b = sig1*u1x*vs + sig2*u2x*vc;
        c = sig1*u1y*vc - sig2*u2y*vs;
        d = sig1*u1y*vs + sig2*u2y*vc;
    }
    float R00 = u1x*vc - u2x*vs, R01 = u1x*vs + u2x*vc;
    float R10 = u1y*vc - u2y*vs, R11 = u1y*vs + u2y*vc;

    float k2mu = 2.0f * mu;
    float fr00 = a - R00, fr01 = b - R01, fr10 = c - R10, fr11 = d - R11;
    float ljj  = lam * J * (J - 1.0f);
    float st00 = k2mu*(fr00*a + fr01*b) + ljj;
    float st01 = k2mu*(fr00*c + fr01*d);
    float st10 = k2mu*(fr10*a + fr11*b);
    float st11 = k2mu*(fr10*c + fr11*d) + ljj;

    // A' = A / P_MASS   (KA = coef/P_MASS)
    float A00 = KA*st00 + C00;
    float A01 = KA*st01 + C01;
    float A10 = KA*st10 + C10;
    float A11 = KA*st11 + C11;

    // fractional position within bin, and b'' = v + A'*(center - x)
    float bxf = floorf(px * INV_DX - 0.5f), byf = floorf(py * INV_DX - 0.5f);
    float fracx = px * INV_DX - bxf - 0.5f;    // in [0,1)
    float fracy = py * INV_DX - byf - 0.5f;
    float bppx = vp.x - DX * (A00*fracx + A01*fracy);
    float bppy = vp.y - DX * (A10*fracx + A11*fracy);

    unsigned qx = (unsigned)fminf(fracx * 65536.0f, 65535.0f);
    unsigned qy = (unsigned)fminf(fracy * 65536.0f, 65535.0f);

    unsigned offv = (rep < 4 ? (o8.x >> (8*rep)) : (o8.y >> (8*(rep-4)))) & 255u;
    int sidx = sb + (int)offv + rk;

    uint4 rec;
    rec.x = qx | (qy << 16);
    rec.y = pack_h2(bppx, bppy);
    rec.z = pack_h2(A00, A01);
    rec.w = pack_h2(A10, A11);
    srec[sidx] = rec;

    F_out4[i]  = make_float4(a, b, c, d);
    mat_out[i] = (float)m;
    Jp_out[i]  = jp;
}

// 16 threads per grid cell: gather 3 row-ranges of compact records; per-record
// column-bin recovered with 2 compares; shuffle-reduce across 16 slices.
__global__ __launch_bounds__(256) void gather_grid_kernel(
    const uint4* __restrict__ srec, const int* __restrict__ starts,
    float2* __restrict__ gv)
{
    // bijective XCD swizzle: nwg = NG2*16/256 = 4096, 4096 % 8 == 0
    int bid  = blockIdx.x;
    int swz  = (bid & 7) * (4096 / 8) + (bid >> 3);
    int gtid  = swz * 256 + threadIdx.x;
    int cell  = gtid >> 4;
    int slice = gtid & 15;
    int gi = cell >> 8, gj = cell & (NG - 1);

    float msum = 0.0f, mvx = 0.0f, mvy = 0.0f;

    // boundaries: rows gi-2..gi, cols gj-2..gj+1 (clamped cols -> empty ranges)
    int b0[4], b1[4], b2[4];
    #pragma unroll
    for (int c = 0; c < 4; ++c) {
        int col = gj - 2 + c;
        int cc = col < 0 ? 0 : col;          // col <= 256 flat-safe
        int bi;
        bi = gi - 2; b0[c] = (bi >= 0) ? starts[(bi << 8) + cc] : 0;
        bi = gi - 1; b1[c] = (bi >= 0) ? starts[(bi << 8) + cc] : 0;
        bi = gi;     b2[c] = starts[(bi << 8) + cc];
    }

    #pragma unroll
    for (int t3 = 0; t3 < 3; ++t3) {
        int s, e, m1, m2;
        if (t3 == 0)      { s = b0[0]; m1 = b0[1]; m2 = b0[2]; e = b0[3]; }
        else if (t3 == 1) { s = b1[0]; m1 = b1[1]; m2 = b1[2]; e = b1[3]; }
        else              { s = b2[0]; m1 = b2[1]; m2 = b2[2]; e = b2[3]; }
        float basex = (float)(t3 - 2);       // bi - gi
        float dgx   = -(basex + 0.5f) * DX;  // pos_gx - center_x  (center = bi+0.5 cells)

        for (int k = s + slice; k < e; k += 16) {
            uint4 r = srec[k];
            int cc = (k >= m1) + (k >= m2);  // column sub-bin: bj = gj-2+cc
            float fx = (float)(r.x & 0xffffu) * (1.0f/65536.0f);
            float fy = (float)(r.x >> 16)     * (1.0f/65536.0f);
            float basey = (float)cc - 2.0f;  // bj - gj  (FIX: was cc-1.5)
            float dgy   = -(basey + 0.5f) * DX;   // = (1.5-cc)*DX (FIX: was (1-cc)*DX)
            float w = bw(basex + 0.5f + fx) * bw(basey + 0.5f + fy);
            float2 bb = unpack_h2(r.y);
            float2 a0 = unpack_h2(r.z);
            float2 a1 = unpack_h2(r.w);
            msum += w;
            mvx  += w * (bb.x + a0.x * dgx + a0.y * dgy);
            mvy  += w * (bb.y + a1.x * dgx + a1.y * dgy);
        }
    }

    #pragma unroll
    for (int off = 1; off < 16; off <<= 1) {
        msum += __shfl_xor(msum, off);
        mvx  += __shfl_xor(mvx,  off);
        mvy  += __shfl_xor(mvy,  off);
    }

    if (slice == 0) {
        float vx = mvx, vy = mvy;
        if (msum > 0.0f) {                   // mass = msum*P_MASS > 0
            float im = 1.0f / fmaxf(msum, MINMS);
            vx *= im; vy *= im;              // P_MASS cancels
        }
        vy -= DT * GRAV;
        if (gi < 3)      vx = fmaxf(vx, 0.0f);
        if (gi >= NG-2)  vx = fminf(vx, 0.0f);
        if (gj < 3)      vy = fmaxf(vy, 0.0f);
        if (gj >= NG-2)  vy = fminf(vy, 0.0f);
        gv[cell] = make_float2(vx, vy);
    }
}

__global__ __launch_bounds__(256) void g2p_kernel(
    const float* __restrict__ x, const float2* __restrict__ gv,
    float* __restrict__ x_out, float* __restrict__ v_out, float* __restrict__ C_out,
    int n)
{
    int i = blockIdx.x * blockDim.x + threadIdx.x;
    if (i >= n) return;

    float2 xp = ((const float2*)x)[i];
    float px = xp.x, py = xp.y;
    float bxf = floorf(px * INV_DX - 0.5f), byf = floorf(py * INV_DX - 0.5f);
    float fx = px * INV_DX - bxf, fy = py * INV_DX - byf;
    float wxs[3] = { 0.5f*(1.5f-fx)*(1.5f-fx), 0.75f-(fx-1.0f)*(fx-1.0f), 0.5f*(fx-0.5f)*(fx-0.5f) };
    float wys[3] = { 0.5f*(1.5f-fy)*(1.5f-fy), 0.75f-(fy-1.0f)*(fy-1.0f), 0.5f*(fy-0.5f)*(fy-0.5f) };
    int bix = (int)bxf, biy = (int)byf;

    float nvx = 0.0f, nvy = 0.0f;
    float c00 = 0.0f, c01 = 0.0f, c10 = 0.0f, c11 = 0.0f;
    #pragma unroll
    for (int ii = 0; ii < 3; ++ii) {
        float posx = (bxf + (float)ii) * DX;
        int rowbase = (bix + ii) * NG + biy;
        #pragma unroll
        for (int jj = 0; jj < 3; ++jj) {
            float w = wxs[ii] * wys[jj];
            float posy = (byf + (float)jj) * DX;
            float2 g = gv[rowbase + jj];
            nvx += w * g.x; nvy += w * g.y;
            c00 += w * g.x * posx; c01 += w * g.x * posy;
            c10 += w * g.y * posx; c11 += w * g.y * posy;
        }
    }
    const float K = 4.0f * INV_DX * INV_DX;
    c00 = (c00 - nvx * px) * K; c01 = (c01 - nvx * py) * K;
    c10 = (c10 - nvy * px) * K; c11 = (c11 - nvy * py) * K;

    ((float2*)x_out)[i] = make_float2(px + DT * nvx, py + DT * nvy);
    ((float2*)v_out)[i] = make_float2(nvx, nvy);
    ((float4*)C_out)[i] = make_float4(c00, c01, c10, c11);
}

extern "C" void kernel_launch(void* const* d_in, const int* in_sizes, int n_in,
                              void* d_out, int out_size, void* d_ws, size_t ws_size,
                              hipStream_t stream) {
    const float* x   = (const float*)d_in[0];
    const float* v   = (const float*)d_in[1];
    const float* C   = (const float*)d_in[2];
    const float* F   = (const float*)d_in[3];
    const int*   mat = (const int*)d_in[4];
    const float* Jp  = (const float*)d_in[5];

    int n = in_sizes[0] / 2;

    float* out     = (float*)d_out;
    float* x_out   = out;
    float* v_out   = out + (size_t)2*n;
    float* C_out   = out + (size_t)4*n;
    float* F_out   = out + (size_t)8*n;
    float* mat_out = out + (size_t)12*n;
    float* Jp_out  = out + (size_t)13*n;

    // srec (16 MB, n x uint4) lives in d_out[0..4n) floats (x/v regions),
    // overwritten by g2p at the very end. Fully written each call.
    uint4* srec = (uint4*)out;

    int blocks = (n + 255) / 256;

    // workspace layout (~4.5 MB)
    char* ws = (char*)d_ws;
    size_t off = 0;
    int*   counts8 = (int*)(ws + off);  off += (size_t)NG2 * NREP * 4;
    int*   starts  = (int*)(ws + off);  off += (size_t)(NG2 + 1) * 4;
    uint2* offs8   = (uint2*)(ws + off); off += (size_t)NG2 * 8;
    int*   bsum    = (int*)(ws + off);  off += 256 * 4;
    unsigned char* rank = (unsigned char*)(ws + off); off += (size_t)n;
    off = (off + 63) & ~(size_t)63;
    float2* gv     = (float2*)(ws + off); off += (size_t)NG2 * 8;

    hipMemsetAsync(counts8, 0, (size_t)NG2 * NREP * 4, stream);
    binrank_kernel<<<blocks, 256, 0, stream>>>(x, counts8, rank, n);
    scan1_kernel<<<NG2/256, 256, 0, stream>>>(counts8, offs8, starts, bsum);
    scan2_kernel<<<1, 256, 0, stream>>>(bsum);
    scan3_kernel<<<NG2/256, 256, 0, stream>>>(starts, bsum, n);
    compute_scatter_kernel<<<blocks, 256, 0, stream>>>(x, v, C, F, mat, Jp,
                                                       starts, offs8, rank, srec,
                                                       (float4*)F_out, mat_out, Jp_out, n);
    gather_grid_kernel<<<(NG2*16)/256, 256, 0, stream>>>(srec, starts, gv);
    g2p_kernel<<<blocks, 256, 0, stream>>>(x, gv, x_out, v_out, C_out, n);
}

// Round 18
// 127.139 us; speedup vs baseline: 1.0191x; 1.0089x over previous
//
#include <hip/hip_runtime.h>
#include <hip/hip_fp16.h>

#define NG 256
#define NG2 (NG*NG)
#define NREP 8                      // counter replicas (contention spreading)

constexpr float DX      = 1.0f / 256.0f;
constexpr float INV_DX  = 256.0f;
constexpr float DT      = 2e-5f;
constexpr float P_VOL   = (1.0f/512.0f) * (1.0f/512.0f);
constexpr float P_MASS  = P_VOL;           // rho = 1
constexpr float MU_0    = 1000.0f / (2.0f * 1.2f);            // E/(2(1+nu))
constexpr float LAM_0   = 1000.0f * 0.2f / (1.2f * 0.6f);     // E nu/((1+nu)(1-2nu))
constexpr float GRAV    = 50.0f;
constexpr float KA      = -DT * 4.0f * INV_DX * INV_DX;       // coef / P_MASS
constexpr float MINMS   = 1e-12f / P_MASS;                    // mass floor in msum units

__device__ __forceinline__ int bin_of(float px, float py) {
    int bx = (int)floorf(px * INV_DX - 0.5f);
    int by = (int)floorf(py * INV_DX - 0.5f);
    bx = min(max(bx, 0), NG - 1);
    by = min(max(by, 0), NG - 1);
    return (bx << 8) | by;
}

// quadratic B-spline weight as a function of (node - particle) distance in cells
__device__ __forceinline__ float bw(float t) {
    float at = fabsf(t);
    float a  = fmaxf(1.5f - at, 0.0f);
    float w1 = 0.75f - t * t;
    float w2 = 0.5f * a * a;
    return (at < 0.5f) ? w1 : w2;
}

__device__ __forceinline__ unsigned pack_h2(float a, float b) {
    union { __half2 h; unsigned u; } cv;
    cv.h = __floats2half2_rn(a, b);
    return cv.u;
}
__device__ __forceinline__ float2 unpack_h2(unsigned u) {
    union { __half2 h; unsigned u; } cv;
    cv.u = u;
    return __half22float2(cv.h);
}

// ---------------- fused particle update + counting (all outputs coalesced) ----------------
// payload[i]: the compact 16B record (frac u16x2, b'' h2, A' rows h2x2)
// meta[i]:    bin (16b) | rep (3b) | rank (13b)   -- rank from replica atomic

__global__ __launch_bounds__(256) void compute_count_kernel(
    const float* __restrict__ x, const float* __restrict__ v,
    const float* __restrict__ C, const float* __restrict__ F,
    const int* __restrict__ mat, const float* __restrict__ Jp,
    int* __restrict__ counts8,
    uint4* __restrict__ payload, unsigned* __restrict__ meta,
    float4* __restrict__ F_out4, float* __restrict__ mat_out, float* __restrict__ Jp_out,
    int n)
{
    int i = blockIdx.x * blockDim.x + threadIdx.x;
    if (i >= n) return;

    float2 xp = ((const float2*)x)[i];
    float px = xp.x, py = xp.y;

    // counting atomic issued early; latency hides under the SVD chain
    int bin = bin_of(px, py);
    int rep = (i >> 8) & (NREP - 1);
    int rk  = atomicAdd(&counts8[rep * NG2 + bin], 1);

    float2 vp = ((const float2*)v)[i];
    float4 Cp = ((const float4*)C)[i];
    float4 Fp = ((const float4*)F)[i];
    int    m  = mat[i];
    float  jp = Jp[i];

    float C00 = Cp.x, C01 = Cp.y, C10 = Cp.z, C11 = Cp.w;
    float a = Fp.x, b = Fp.y, c = Fp.z, d = Fp.w;

    // F += dt * C @ F
    float na = a + DT*(C00*a + C01*c);
    float nb = b + DT*(C00*b + C01*d);
    float nc = c + DT*(C10*a + C11*c);
    float nd = d + DT*(C10*b + C11*d);
    a = na; b = nb; c = nc; d = nd;

    float h = expf(10.0f * (1.0f - jp));
    if (m == 1) h = 0.3f;
    float mu  = (m == 0) ? 0.0f : MU_0 * h;
    float lam = LAM_0 * h;

    // closed-form 2x2 SVD via eigendecomposition of A^T A
    float S00 = a*a + c*c, S01 = a*b + c*d, S11 = b*b + d*d;
    float mh = 0.5f*(S00 + S11), dh = 0.5f*(S00 - S11);
    float delta = sqrtf(dh*dh + S01*S01);
    float sig1 = sqrtf(fmaxf(mh + delta, 0.0f));
    float sig2 = sqrtf(fmaxf(mh - delta, 0.0f));
    float e0, e1;
    if (dh >= 0.0f) { e0 = delta + dh; e1 = S01; }
    else            { e0 = S01;        e1 = delta - dh; }
    float elen = sqrtf(e0*e0 + e1*e1);
    float vc, vs;
    if (elen > 1e-30f) { float il = 1.0f/elen; vc = e0*il; vs = e1*il; }
    else               { vc = 1.0f; vs = 0.0f; }
    float inv1 = 1.0f / fmaxf(sig1, 1e-30f);
    float inv2 = 1.0f / fmaxf(sig2, 1e-30f);
    float u1x = ( a*vc + b*vs) * inv1, u1y = ( c*vc + d*vs) * inv1;
    float u2x = (-a*vs + b*vc) * inv2, u2y = (-c*vs + d*vc) * inv2;

    if (m == 2) {   // snow plasticity
        float c1 = fminf(fmaxf(sig1, 1.0f - 2.5e-2f), 1.0f + 4.5e-3f);
        float c2 = fminf(fmaxf(sig2, 1.0f - 2.5e-2f), 1.0f + 4.5e-3f);
        jp = jp * (sig1 / c1) * (sig2 / c2);
        sig1 = c1; sig2 = c2;
    }
    float J = sig1 * sig2;

    if (m == 0) {              // fluid: F = sqrt(J) I
        float s = sqrtf(J);
        a = s; b = 0.0f; c = 0.0f; d = s;
    } else if (m == 2) {       // snow: F = U diag(sig) Vh
        a = sig1*u1x*vc - sig2*u2x*vs;
        b = sig1*u1x*vs + sig2*u2x*vc;
        c = sig1*u1y*vc - sig2*u2y*vs;
        d = sig1*u1y*vs + sig2*u2y*vc;
    }
    float R00 = u1x*vc - u2x*vs, R01 = u1x*vs + u2x*vc;
    float R10 = u1y*vc - u2y*vs, R11 = u1y*vs + u2y*vc;

    float k2mu = 2.0f * mu;
    float fr00 = a - R00, fr01 = b - R01, fr10 = c - R10, fr11 = d - R11;
    float ljj  = lam * J * (J - 1.0f);
    float st00 = k2mu*(fr00*a + fr01*b) + ljj;
    float st01 = k2mu*(fr00*c + fr01*d);
    float st10 = k2mu*(fr10*a + fr11*b);
    float st11 = k2mu*(fr10*c + fr11*d) + ljj;

    // A' = A / P_MASS   (KA = coef/P_MASS)
    float A00 = KA*st00 + C00;
    float A01 = KA*st01 + C01;
    float A10 = KA*st10 + C10;
    float A11 = KA*st11 + C11;

    // fractional position within bin, and b'' = v + A'*(center - x)
    float bxf = floorf(px * INV_DX - 0.5f), byf = floorf(py * INV_DX - 0.5f);
    float fracx = px * INV_DX - bxf - 0.5f;    // in [0,1)
    float fracy = py * INV_DX - byf - 0.5f;
    float bppx = vp.x - DX * (A00*fracx + A01*fracy);
    float bppy = vp.y - DX * (A10*fracx + A11*fracy);

    unsigned qx = (unsigned)fminf(fracx * 65536.0f, 65535.0f);
    unsigned qy = (unsigned)fminf(fracy * 65536.0f, 65535.0f);

    uint4 rec;
    rec.x = qx | (qy << 16);
    rec.y = pack_h2(bppx, bppy);
    rec.z = pack_h2(A00, A01);
    rec.w = pack_h2(A10, A11);
    payload[i] = rec;                              // coalesced
    meta[i] = (unsigned)bin | ((unsigned)rep << 16) | ((unsigned)rk << 19);

    F_out4[i]  = make_float4(a, b, c, d);
    mat_out[i] = (float)m;
    Jp_out[i]  = jp;
}

// ---------------- scans (counts8 -> starts + packed intra-bin offsets) ----------------

__global__ __launch_bounds__(256) void scan1_kernel(
    const int* __restrict__ counts8, uint2* __restrict__ offs8,
    int* __restrict__ starts, int* __restrict__ bsum)
{
    __shared__ int tmp[256];
    int t = threadIdx.x, blk = blockIdx.x;
    int b = blk * 256 + t;

    int c0 = counts8[0*NG2 + b], c1 = counts8[1*NG2 + b];
    int c2 = counts8[2*NG2 + b], c3 = counts8[3*NG2 + b];
    int c4 = counts8[4*NG2 + b], c5 = counts8[5*NG2 + b];
    int c6 = counts8[6*NG2 + b], c7 = counts8[7*NG2 + b];
    int o1 = c0, o2 = o1+c1, o3 = o2+c2, o4 = o3+c3;
    int o5 = o4+c4, o6 = o5+c5, o7 = o6+c6;
    int total = o7 + c7;
    uint2 packed;
    packed.x = (unsigned)(o1 << 8) | ((unsigned)o2 << 16) | ((unsigned)o3 << 24);
    packed.y = (unsigned)o4 | ((unsigned)o5 << 8) | ((unsigned)o6 << 16) | ((unsigned)o7 << 24);
    offs8[b] = packed;

    tmp[t] = total;
    __syncthreads();
    #pragma unroll
    for (int off = 1; off < 256; off <<= 1) {
        int add = (t >= off) ? tmp[t - off] : 0;
        __syncthreads();
        tmp[t] += add;
        __syncthreads();
    }
    starts[b] = tmp[t] - total;
    if (t == 255) bsum[blk] = tmp[255];
}

__global__ __launch_bounds__(256) void scan2_kernel(int* __restrict__ bsum)
{
    __shared__ int tmp[256];
    int t = threadIdx.x;
    int v = bsum[t];
    tmp[t] = v;
    __syncthreads();
    #pragma unroll
    for (int off = 1; off < 256; off <<= 1) {
        int add = (t >= off) ? tmp[t - off] : 0;
        __syncthreads();
        tmp[t] += add;
        __syncthreads();
    }
    bsum[t] = tmp[t] - v;
}

__global__ __launch_bounds__(256) void scan3_kernel(
    int* __restrict__ starts, const int* __restrict__ bsum, int n)
{
    int i = blockIdx.x * blockDim.x + threadIdx.x;
    if (i < NG2) starts[i] += bsum[i >> 8];
    if (i == 0) starts[NG2] = n;
}

// ---------------- mover: pure permutation (random requests only) ----------------

__global__ __launch_bounds__(256) void mover_kernel(
    const uint4* __restrict__ payload, const unsigned* __restrict__ meta,
    const int* __restrict__ starts, const uint2* __restrict__ offs8,
    uint4* __restrict__ srec, int n)
{
    int i = blockIdx.x * blockDim.x + threadIdx.x;
    if (i >= n) return;
    unsigned mt = meta[i];
    int bin = (int)(mt & 0xffffu);
    int rep = (int)((mt >> 16) & 7u);
    int rk  = (int)(mt >> 19);
    uint2 o8 = offs8[bin];
    int sb = starts[bin];
    unsigned offv = (rep < 4 ? (o8.x >> (8*rep)) : (o8.y >> (8*(rep-4)))) & 255u;
    srec[sb + (int)offv + rk] = payload[i];
}

// 16 threads per grid cell: gather 3 row-ranges of compact records; per-record
// column-bin recovered with 2 compares; shuffle-reduce across 16 slices.
__global__ __launch_bounds__(256) void gather_grid_kernel(
    const uint4* __restrict__ srec, const int* __restrict__ starts,
    float2* __restrict__ gv)
{
    // bijective XCD swizzle: nwg = NG2*16/256 = 4096, 4096 % 8 == 0
    int bid  = blockIdx.x;
    int swz  = (bid & 7) * (4096 / 8) + (bid >> 3);
    int gtid  = swz * 256 + threadIdx.x;
    int cell  = gtid >> 4;
    int slice = gtid & 15;
    int gi = cell >> 8, gj = cell & (NG - 1);

    float msum = 0.0f, mvx = 0.0f, mvy = 0.0f;

    // boundaries: rows gi-2..gi, cols gj-2..gj+1 (clamped cols -> empty ranges)
    int b0[4], b1[4], b2[4];
    #pragma unroll
    for (int c = 0; c < 4; ++c) {
        int col = gj - 2 + c;
        int cc = col < 0 ? 0 : col;          // col <= 256 flat-safe
        int bi;
        bi = gi - 2; b0[c] = (bi >= 0) ? starts[(bi << 8) + cc] : 0;
        bi = gi - 1; b1[c] = (bi >= 0) ? starts[(bi << 8) + cc] : 0;
        bi = gi;     b2[c] = starts[(bi << 8) + cc];
    }

    #pragma unroll
    for (int t3 = 0; t3 < 3; ++t3) {
        int s, e, m1, m2;
        if (t3 == 0)      { s = b0[0]; m1 = b0[1]; m2 = b0[2]; e = b0[3]; }
        else if (t3 == 1) { s = b1[0]; m1 = b1[1]; m2 = b1[2]; e = b1[3]; }
        else              { s = b2[0]; m1 = b2[1]; m2 = b2[2]; e = b2[3]; }
        float basex = (float)(t3 - 2);       // bi - gi
        float dgx   = -(basex + 0.5f) * DX;  // pos_gx - center_x

        for (int k = s + slice; k < e; k += 16) {
            uint4 r = srec[k];
            int cc = (k >= m1) + (k >= m2);  // column sub-bin: bj = gj-2+cc
            float fx = (float)(r.x & 0xffffu) * (1.0f/65536.0f);
            float fy = (float)(r.x >> 16)     * (1.0f/65536.0f);
            float basey = (float)cc - 2.0f;  // bj - gj
            float dgy   = -(basey + 0.5f) * DX;
            float w = bw(basex + 0.5f + fx) * bw(basey + 0.5f + fy);
            float2 bb = unpack_h2(r.y);
            float2 a0 = unpack_h2(r.z);
            float2 a1 = unpack_h2(r.w);
            msum += w;
            mvx  += w * (bb.x + a0.x * dgx + a0.y * dgy);
            mvy  += w * (bb.y + a1.x * dgx + a1.y * dgy);
        }
    }

    #pragma unroll
    for (int off = 1; off < 16; off <<= 1) {
        msum += __shfl_xor(msum, off);
        mvx  += __shfl_xor(mvx,  off);
        mvy  += __shfl_xor(mvy,  off);
    }

    if (slice == 0) {
        float vx = mvx, vy = mvy;
        if (msum > 0.0f) {                   // mass = msum*P_MASS > 0
            float im = 1.0f / fmaxf(msum, MINMS);
            vx *= im; vy *= im;              // P_MASS cancels
        }
        vy -= DT * GRAV;
        if (gi < 3)      vx = fmaxf(vx, 0.0f);
        if (gi >= NG-2)  vx = fminf(vx, 0.0f);
        if (gj < 3)      vy = fmaxf(vy, 0.0f);
        if (gj >= NG-2)  vy = fminf(vy, 0.0f);
        gv[cell] = make_float2(vx, vy);
    }
}

__global__ __launch_bounds__(256) void g2p_kernel(
    const float* __restrict__ x, const float2* __restrict__ gv,
    float* __restrict__ x_out, float* __restrict__ v_out, float* __restrict__ C_out,
    int n)
{
    int i = blockIdx.x * blockDim.x + threadIdx.x;
    if (i >= n) return;

    float2 xp = ((const float2*)x)[i];
    float px = xp.x, py = xp.y;
    float bxf = floorf(px * INV_DX - 0.5f), byf = floorf(py * INV_DX - 0.5f);
    float fx = px * INV_DX - bxf, fy = py * INV_DX - byf;
    float wxs[3] = { 0.5f*(1.5f-fx)*(1.5f-fx), 0.75f-(fx-1.0f)*(fx-1.0f), 0.5f*(fx-0.5f)*(fx-0.5f) };
    float wys[3] = { 0.5f*(1.5f-fy)*(1.5f-fy), 0.75f-(fy-1.0f)*(fy-1.0f), 0.5f*(fy-0.5f)*(fy-0.5f) };
    int bix = (int)bxf, biy = (int)byf;

    float nvx = 0.0f, nvy = 0.0f;
    float c00 = 0.0f, c01 = 0.0f, c10 = 0.0f, c11 = 0.0f;
    #pragma unroll
    for (int ii = 0; ii < 3; ++ii) {
        float posx = (bxf + (float)ii) * DX;
        int rowbase = (bix + ii) * NG + biy;
        #pragma unroll
        for (int jj = 0; jj < 3; ++jj) {
            float w = wxs[ii] * wys[jj];
            float posy = (byf + (float)jj) * DX;
            float2 g = gv[rowbase + jj];
            nvx += w * g.x; nvy += w * g.y;
            c00 += w * g.x * posx; c01 += w * g.x * posy;
            c10 += w * g.y * posx; c11 += w * g.y * posy;
        }
    }
    const float K = 4.0f * INV_DX * INV_DX;
    c00 = (c00 - nvx * px) * K; c01 = (c01 - nvx * py) * K;
    c10 = (c10 - nvy * px) * K; c11 = (c11 - nvy * py) * K;

    ((float2*)x_out)[i] = make_float2(px + DT * nvx, py + DT * nvy);
    ((float2*)v_out)[i] = make_float2(nvx, nvy);
    ((float4*)C_out)[i] = make_float4(c00, c01, c10, c11);
}

extern "C" void kernel_launch(void* const* d_in, const int* in_sizes, int n_in,
                              void* d_out, int out_size, void* d_ws, size_t ws_size,
                              hipStream_t stream) {
    const float* x   = (const float*)d_in[0];
    const float* v   = (const float*)d_in[1];
    const float* C   = (const float*)d_in[2];
    const float* F   = (const float*)d_in[3];
    const int*   mat = (const int*)d_in[4];
    const float* Jp  = (const float*)d_in[5];

    int n = in_sizes[0] / 2;

    float* out     = (float*)d_out;
    float* x_out   = out;
    float* v_out   = out + (size_t)2*n;
    float* C_out   = out + (size_t)4*n;
    float* F_out   = out + (size_t)8*n;
    float* mat_out = out + (size_t)12*n;
    float* Jp_out  = out + (size_t)13*n;

    // srec (16 MB, n x uint4) lives in d_out[0..4n) floats (x/v regions),
    // overwritten by g2p at the very end. Fully written each call.
    uint4* srec = (uint4*)out;

    int blocks = (n + 255) / 256;

    // workspace layout (~23.3 MB)
    char* ws = (char*)d_ws;
    size_t off = 0;
    int*   counts8 = (int*)(ws + off);  off += (size_t)NG2 * NREP * 4;
    int*   starts  = (int*)(ws + off);  off += (size_t)(NG2 + 1) * 4;
    uint2* offs8   = (uint2*)(ws + off); off += (size_t)NG2 * 8;
    int*   bsum    = (int*)(ws + off);  off += 256 * 4;
    off = (off + 63) & ~(size_t)63;
    uint4* payload = (uint4*)(ws + off); off += (size_t)n * 16;
    unsigned* meta = (unsigned*)(ws + off); off += (size_t)n * 4;
    off = (off + 63) & ~(size_t)63;
    float2* gv     = (float2*)(ws + off); off += (size_t)NG2 * 8;

    hipMemsetAsync(counts8, 0, (size_t)NG2 * NREP * 4, stream);
    compute_count_kernel<<<blocks, 256, 0, stream>>>(x, v, C, F, mat, Jp,
                                                     counts8, payload, meta,
                                                     (float4*)F_out, mat_out, Jp_out, n);
    scan1_kernel<<<NG2/256, 256, 0, stream>>>(counts8, offs8, starts, bsum);
    scan2_kernel<<<1, 256, 0, stream>>>(bsum);
    scan3_kernel<<<NG2/256, 256, 0, stream>>>(starts, bsum, n);
    mover_kernel<<<blocks, 256, 0, stream>>>(payload, meta, starts, offs8, srec, n);
    gather_grid_kernel<<<(NG2*16)/256, 256, 0, stream>>>(srec, starts, gv);
    g2p_kernel<<<blocks, 256, 0, stream>>>(x, gv, x_out, v_out, C_out, n);
}

// Round 19
// 126.123 us; speedup vs baseline: 1.0273x; 1.0081x over previous
//
#include <hip/hip_runtime.h>
#include <hip/hip_fp16.h>

#define NG 256
#define NG2 (NG*NG)
#define NREP 8                      // counter replicas = 8 XCDs

constexpr float DX      = 1.0f / 256.0f;
constexpr float INV_DX  = 256.0f;
constexpr float DT      = 2e-5f;
constexpr float P_VOL   = (1.0f/512.0f) * (1.0f/512.0f);
constexpr float P_MASS  = P_VOL;           // rho = 1
constexpr float MU_0    = 1000.0f / (2.0f * 1.2f);            // E/(2(1+nu))
constexpr float LAM_0   = 1000.0f * 0.2f / (1.2f * 0.6f);     // E nu/((1+nu)(1-2nu))
constexpr float GRAV    = 50.0f;
constexpr float KA      = -DT * 4.0f * INV_DX * INV_DX;       // coef / P_MASS
constexpr float MINMS   = 1e-12f / P_MASS;                    // mass floor in msum units

__device__ __forceinline__ int bin_of(float px, float py) {
    int bx = (int)floorf(px * INV_DX - 0.5f);
    int by = (int)floorf(py * INV_DX - 0.5f);
    bx = min(max(bx, 0), NG - 1);
    by = min(max(by, 0), NG - 1);
    return (bx << 8) | by;
}

// physical XCD id (0..7) — wave-uniform; HW-verified on gfx950 (learn_hip m09)
__device__ __forceinline__ int xcc_id() {
    unsigned v;
    asm volatile("s_getreg_b32 %0, hwreg(HW_REG_XCC_ID)" : "=s"(v));
    return (int)(v & (NREP - 1));
}

// quadratic B-spline weight as a function of (node - particle) distance in cells
__device__ __forceinline__ float bw(float t) {
    float at = fabsf(t);
    float a  = fmaxf(1.5f - at, 0.0f);
    float w1 = 0.75f - t * t;
    float w2 = 0.5f * a * a;
    return (at < 0.5f) ? w1 : w2;
}

__device__ __forceinline__ unsigned pack_h2(float a, float b) {
    union { __half2 h; unsigned u; } cv;
    cv.h = __floats2half2_rn(a, b);
    return cv.u;
}
__device__ __forceinline__ float2 unpack_h2(unsigned u) {
    union { __half2 h; unsigned u; } cv;
    cv.u = u;
    return __half22float2(cv.h);
}

// ---------------- fused particle update + counting (all outputs coalesced) ----------------
// payload[i]: the compact 16B record (frac u16x2, b'' h2, A' rows h2x2)
// meta[i]:    bin (16b) | rep (3b) | rank (13b)   -- rank from XCD-local atomic

__global__ __launch_bounds__(256) void compute_count_kernel(
    const float* __restrict__ x, const float* __restrict__ v,
    const float* __restrict__ C, const float* __restrict__ F,
    const int* __restrict__ mat, const float* __restrict__ Jp,
    int* __restrict__ counts8,
    uint4* __restrict__ payload, unsigned* __restrict__ meta,
    float4* __restrict__ F_out4, float* __restrict__ mat_out, float* __restrict__ Jp_out,
    int n)
{
    int i = blockIdx.x * blockDim.x + threadIdx.x;
    if (i >= n) return;

    float2 xp = ((const float2*)x)[i];
    float px = xp.x, py = xp.y;

    // counting atomic: replica = PHYSICAL XCD -> the counter line stays in this
    // XCD's L2 (no cross-XCD ping-pong). Issued early; hides under SVD chain.
    int bin = bin_of(px, py);
    int rep = xcc_id();
    int rk  = atomicAdd(&counts8[rep * NG2 + bin], 1);

    float2 vp = ((const float2*)v)[i];
    float4 Cp = ((const float4*)C)[i];
    float4 Fp = ((const float4*)F)[i];
    int    m  = mat[i];
    float  jp = Jp[i];

    float C00 = Cp.x, C01 = Cp.y, C10 = Cp.z, C11 = Cp.w;
    float a = Fp.x, b = Fp.y, c = Fp.z, d = Fp.w;

    // F += dt * C @ F
    float na = a + DT*(C00*a + C01*c);
    float nb = b + DT*(C00*b + C01*d);
    float nc = c + DT*(C10*a + C11*c);
    float nd = d + DT*(C10*b + C11*d);
    a = na; b = nb; c = nc; d = nd;

    float h = expf(10.0f * (1.0f - jp));
    if (m == 1) h = 0.3f;
    float mu  = (m == 0) ? 0.0f : MU_0 * h;
    float lam = LAM_0 * h;

    // closed-form 2x2 SVD via eigendecomposition of A^T A
    float S00 = a*a + c*c, S01 = a*b + c*d, S11 = b*b + d*d;
    float mh = 0.5f*(S00 + S11), dh = 0.5f*(S00 - S11);
    float delta = sqrtf(dh*dh + S01*S01);
    float sig1 = sqrtf(fmaxf(mh + delta, 0.0f));
    float sig2 = sqrtf(fmaxf(mh - delta, 0.0f));
    float e0, e1;
    if (dh >= 0.0f) { e0 = delta + dh; e1 = S01; }
    else            { e0 = S01;        e1 = delta - dh; }
    float elen = sqrtf(e0*e0 + e1*e1);
    float vc, vs;
    if (elen > 1e-30f) { float il = 1.0f/elen; vc = e0*il; vs = e1*il; }
    else               { vc = 1.0f; vs = 0.0f; }
    float inv1 = 1.0f / fmaxf(sig1, 1e-30f);
    float inv2 = 1.0f / fmaxf(sig2, 1e-30f);
    float u1x = ( a*vc + b*vs) * inv1, u1y = ( c*vc + d*vs) * inv1;
    float u2x = (-a*vs + b*vc) * inv2, u2y = (-c*vs + d*vc) * inv2;

    if (m == 2) {   // snow plasticity
        float c1 = fminf(fmaxf(sig1, 1.0f - 2.5e-2f), 1.0f + 4.5e-3f);
        float c2 = fminf(fmaxf(sig2, 1.0f - 2.5e-2f), 1.0f + 4.5e-3f);
        jp = jp * (sig1 / c1) * (sig2 / c2);
        sig1 = c1; sig2 = c2;
    }
    float J = sig1 * sig2;

    if (m == 0) {              // fluid: F = sqrt(J) I
        float s = sqrtf(J);
        a = s; b = 0.0f; c = 0.0f; d = s;
    } else if (m == 2) {       // snow: F = U diag(sig) Vh
        a = sig1*u1x*vc - sig2*u2x*vs;
        b = sig1*u1x*vs + sig2*u2x*vc;
        c = sig1*u1y*vc - sig2*u2y*vs;
        d = sig1*u1y*vs + sig2*u2y*vc;
    }
    float R00 = u1x*vc - u2x*vs, R01 = u1x*vs + u2x*vc;
    float R10 = u1y*vc - u2y*vs, R11 = u1y*vs + u2y*vc;

    float k2mu = 2.0f * mu;
    float fr00 = a - R00, fr01 = b - R01, fr10 = c - R10, fr11 = d - R11;
    float ljj  = lam * J * (J - 1.0f);
    float st00 = k2mu*(fr00*a + fr01*b) + ljj;
    float st01 = k2mu*(fr00*c + fr01*d);
    float st10 = k2mu*(fr10*a + fr11*b);
    float st11 = k2mu*(fr10*c + fr11*d) + ljj;

    // A' = A / P_MASS   (KA = coef/P_MASS)
    float A00 = KA*st00 + C00;
    float A01 = KA*st01 + C01;
    float A10 = KA*st10 + C10;
    float A11 = KA*st11 + C11;

    // fractional position within bin, and b'' = v + A'*(center - x)
    float bxf = floorf(px * INV_DX - 0.5f), byf = floorf(py * INV_DX - 0.5f);
    float fracx = px * INV_DX - bxf - 0.5f;    // in [0,1)
    float fracy = py * INV_DX - byf - 0.5f;
    float bppx = vp.x - DX * (A00*fracx + A01*fracy);
    float bppy = vp.y - DX * (A10*fracx + A11*fracy);

    unsigned qx = (unsigned)fminf(fracx * 65536.0f, 65535.0f);
    unsigned qy = (unsigned)fminf(fracy * 65536.0f, 65535.0f);

    uint4 rec;
    rec.x = qx | (qy << 16);
    rec.y = pack_h2(bppx, bppy);
    rec.z = pack_h2(A00, A01);
    rec.w = pack_h2(A10, A11);
    payload[i] = rec;                              // coalesced
    meta[i] = (unsigned)bin | ((unsigned)rep << 16) | ((unsigned)rk << 19);

    F_out4[i]  = make_float4(a, b, c, d);
    mat_out[i] = (float)m;
    Jp_out[i]  = jp;
}

// ---------------- scans (counts8 -> starts + packed intra-bin offsets) ----------------

__global__ __launch_bounds__(256) void scan1_kernel(
    const int* __restrict__ counts8, uint2* __restrict__ offs8,
    int* __restrict__ starts, int* __restrict__ bsum)
{
    __shared__ int tmp[256];
    int t = threadIdx.x, blk = blockIdx.x;
    int b = blk * 256 + t;

    int c0 = counts8[0*NG2 + b], c1 = counts8[1*NG2 + b];
    int c2 = counts8[2*NG2 + b], c3 = counts8[3*NG2 + b];
    int c4 = counts8[4*NG2 + b], c5 = counts8[5*NG2 + b];
    int c6 = counts8[6*NG2 + b], c7 = counts8[7*NG2 + b];
    int o1 = c0, o2 = o1+c1, o3 = o2+c2, o4 = o3+c3;
    int o5 = o4+c4, o6 = o5+c5, o7 = o6+c6;
    int total = o7 + c7;
    uint2 packed;
    packed.x = (unsigned)(o1 << 8) | ((unsigned)o2 << 16) | ((unsigned)o3 << 24);
    packed.y = (unsigned)o4 | ((unsigned)o5 << 8) | ((unsigned)o6 << 16) | ((unsigned)o7 << 24);
    offs8[b] = packed;

    tmp[t] = total;
    __syncthreads();
    #pragma unroll
    for (int off = 1; off < 256; off <<= 1) {
        int add = (t >= off) ? tmp[t - off] : 0;
        __syncthreads();
        tmp[t] += add;
        __syncthreads();
    }
    starts[b] = tmp[t] - total;
    if (t == 255) bsum[blk] = tmp[255];
}

__global__ __launch_bounds__(256) void scan2_kernel(int* __restrict__ bsum)
{
    __shared__ int tmp[256];
    int t = threadIdx.x;
    int v = bsum[t];
    tmp[t] = v;
    __syncthreads();
    #pragma unroll
    for (int off = 1; off < 256; off <<= 1) {
        int add = (t >= off) ? tmp[t - off] : 0;
        __syncthreads();
        tmp[t] += add;
        __syncthreads();
    }
    bsum[t] = tmp[t] - v;
}

__global__ __launch_bounds__(256) void scan3_kernel(
    int* __restrict__ starts, const int* __restrict__ bsum, int n)
{
    int i = blockIdx.x * blockDim.x + threadIdx.x;
    if (i < NG2) starts[i] += bsum[i >> 8];
    if (i == 0) starts[NG2] = n;
}

// ---------------- mover: pure permutation (random requests only) ----------------

__global__ __launch_bounds__(256) void mover_kernel(
    const uint4* __restrict__ payload, const unsigned* __restrict__ meta,
    const int* __restrict__ starts, const uint2* __restrict__ offs8,
    uint4* __restrict__ srec, int n)
{
    int i = blockIdx.x * blockDim.x + threadIdx.x;
    if (i >= n) return;
    unsigned mt = meta[i];
    int bin = (int)(mt & 0xffffu);
    int rep = (int)((mt >> 16) & 7u);
    int rk  = (int)(mt >> 19);
    uint2 o8 = offs8[bin];
    int sb = starts[bin];
    unsigned offv = (rep < 4 ? (o8.x >> (8*rep)) : (o8.y >> (8*(rep-4)))) & 255u;
    srec[sb + (int)offv + rk] = payload[i];
}

// 16 threads per grid cell: gather 3 row-ranges of compact records; per-record
// column-bin recovered with 2 compares; shuffle-reduce across 16 slices.
__global__ __launch_bounds__(256) void gather_grid_kernel(
    const uint4* __restrict__ srec, const int* __restrict__ starts,
    float2* __restrict__ gv)
{
    // bijective XCD swizzle: nwg = NG2*16/256 = 4096, 4096 % 8 == 0
    int bid  = blockIdx.x;
    int swz  = (bid & 7) * (4096 / 8) + (bid >> 3);
    int gtid  = swz * 256 + threadIdx.x;
    int cell  = gtid >> 4;
    int slice = gtid & 15;
    int gi = cell >> 8, gj = cell & (NG - 1);

    float msum = 0.0f, mvx = 0.0f, mvy = 0.0f;

    // boundaries: rows gi-2..gi, cols gj-2..gj+1 (clamped cols -> empty ranges)
    int b0[4], b1[4], b2[4];
    #pragma unroll
    for (int c = 0; c < 4; ++c) {
        int col = gj - 2 + c;
        int cc = col < 0 ? 0 : col;          // col <= 256 flat-safe
        int bi;
        bi = gi - 2; b0[c] = (bi >= 0) ? starts[(bi << 8) + cc] : 0;
        bi = gi - 1; b1[c] = (bi >= 0) ? starts[(bi << 8) + cc] : 0;
        bi = gi;     b2[c] = starts[(bi << 8) + cc];
    }

    #pragma unroll
    for (int t3 = 0; t3 < 3; ++t3) {
        int s, e, m1, m2;
        if (t3 == 0)      { s = b0[0]; m1 = b0[1]; m2 = b0[2]; e = b0[3]; }
        else if (t3 == 1) { s = b1[0]; m1 = b1[1]; m2 = b1[2]; e = b1[3]; }
        else              { s = b2[0]; m1 = b2[1]; m2 = b2[2]; e = b2[3]; }
        float basex = (float)(t3 - 2);       // bi - gi
        float dgx   = -(basex + 0.5f) * DX;  // pos_gx - center_x

        for (int k = s + slice; k < e; k += 16) {
            uint4 r = srec[k];
            int cc = (k >= m1) + (k >= m2);  // column sub-bin: bj = gj-2+cc
            float fx = (float)(r.x & 0xffffu) * (1.0f/65536.0f);
            float fy = (float)(r.x >> 16)     * (1.0f/65536.0f);
            float basey = (float)cc - 2.0f;  // bj - gj
            float dgy   = -(basey + 0.5f) * DX;
            float w = bw(basex + 0.5f + fx) * bw(basey + 0.5f + fy);
            float2 bb = unpack_h2(r.y);
            float2 a0 = unpack_h2(r.z);
            float2 a1 = unpack_h2(r.w);
            msum += w;
            mvx  += w * (bb.x + a0.x * dgx + a0.y * dgy);
            mvy  += w * (bb.y + a1.x * dgx + a1.y * dgy);
        }
    }

    #pragma unroll
    for (int off = 1; off < 16; off <<= 1) {
        msum += __shfl_xor(msum, off);
        mvx  += __shfl_xor(mvx,  off);
        mvy  += __shfl_xor(mvy,  off);
    }

    if (slice == 0) {
        float vx = mvx, vy = mvy;
        if (msum > 0.0f) {                   // mass = msum*P_MASS > 0
            float im = 1.0f / fmaxf(msum, MINMS);
            vx *= im; vy *= im;              // P_MASS cancels
        }
        vy -= DT * GRAV;
        if (gi < 3)      vx = fmaxf(vx, 0.0f);
        if (gi >= NG-2)  vx = fminf(vx, 0.0f);
        if (gj < 3)      vy = fmaxf(vy, 0.0f);
        if (gj >= NG-2)  vy = fminf(vy, 0.0f);
        gv[cell] = make_float2(vx, vy);
    }
}

__global__ __launch_bounds__(256) void g2p_kernel(
    const float* __restrict__ x, const float2* __restrict__ gv,
    float* __restrict__ x_out, float* __restrict__ v_out, float* __restrict__ C_out,
    int n)
{
    int i = blockIdx.x * blockDim.x + threadIdx.x;
    if (i >= n) return;

    float2 xp = ((const float2*)x)[i];
    float px = xp.x, py = xp.y;
    float bxf = floorf(px * INV_DX - 0.5f), byf = floorf(py * INV_DX - 0.5f);
    float fx = px * INV_DX - bxf, fy = py * INV_DX - byf;
    float wxs[3] = { 0.5f*(1.5f-fx)*(1.5f-fx), 0.75f-(fx-1.0f)*(fx-1.0f), 0.5f*(fx-0.5f)*(fx-0.5f) };
    float wys[3] = { 0.5f*(1.5f-fy)*(1.5f-fy), 0.75f-(fy-1.0f)*(fy-1.0f), 0.5f*(fy-0.5f)*(fy-0.5f) };
    int bix = (int)bxf, biy = (int)byf;

    float nvx = 0.0f, nvy = 0.0f;
    float c00 = 0.0f, c01 = 0.0f, c10 = 0.0f, c11 = 0.0f;
    #pragma unroll
    for (int ii = 0; ii < 3; ++ii) {
        float posx = (bxf + (float)ii) * DX;
        int rowbase = (bix + ii) * NG + biy;
        #pragma unroll
        for (int jj = 0; jj < 3; ++jj) {
            float w = wxs[ii] * wys[jj];
            float posy = (byf + (float)jj) * DX;
            float2 g = gv[rowbase + jj];
            nvx += w * g.x; nvy += w * g.y;
            c00 += w * g.x * posx; c01 += w * g.x * posy;
            c10 += w * g.y * posx; c11 += w * g.y * posy;
        }
    }
    const float K = 4.0f * INV_DX * INV_DX;
    c00 = (c00 - nvx * px) * K; c01 = (c01 - nvx * py) * K;
    c10 = (c10 - nvy * px) * K; c11 = (c11 - nvy * py) * K;

    ((float2*)x_out)[i] = make_float2(px + DT * nvx, py + DT * nvy);
    ((float2*)v_out)[i] = make_float2(nvx, nvy);
    ((float4*)C_out)[i] = make_float4(c00, c01, c10, c11);
}

extern "C" void kernel_launch(void* const* d_in, const int* in_sizes, int n_in,
                              void* d_out, int out_size, void* d_ws, size_t ws_size,
                              hipStream_t stream) {
    const float* x   = (const float*)d_in[0];
    const float* v   = (const float*)d_in[1];
    const float* C   = (const float*)d_in[2];
    const float* F   = (const float*)d_in[3];
    const int*   mat = (const int*)d_in[4];
    const float* Jp  = (const float*)d_in[5];

    int n = in_sizes[0] / 2;

    float* out     = (float*)d_out;
    float* x_out   = out;
    float* v_out   = out + (size_t)2*n;
    float* C_out   = out + (size_t)4*n;
    float* F_out   = out + (size_t)8*n;
    float* mat_out = out + (size_t)12*n;
    float* Jp_out  = out + (size_t)13*n;

    // srec (16 MB, n x uint4) lives in d_out[0..4n) floats (x/v regions),
    // overwritten by g2p at the very end. Fully written each call.
    uint4* srec = (uint4*)out;

    int blocks = (n + 255) / 256;

    // workspace layout (~23.3 MB)
    char* ws = (char*)d_ws;
    size_t off = 0;
    int*   counts8 = (int*)(ws + off);  off += (size_t)NG2 * NREP * 4;
    int*   starts  = (int*)(ws + off);  off += (size_t)(NG2 + 1) * 4;
    uint2* offs8   = (uint2*)(ws + off); off += (size_t)NG2 * 8;
    int*   bsum    = (int*)(ws + off);  off += 256 * 4;
    off = (off + 63) & ~(size_t)63;
    uint4* payload = (uint4*)(ws + off); off += (size_t)n * 16;
    unsigned* meta = (unsigned*)(ws + off); off += (size_t)n * 4;
    off = (off + 63) & ~(size_t)63;
    float2* gv     = (float2*)(ws + off); off += (size_t)NG2 * 8;

    hipMemsetAsync(counts8, 0, (size_t)NG2 * NREP * 4, stream);
    compute_count_kernel<<<blocks, 256, 0, stream>>>(x, v, C, F, mat, Jp,
                                                     counts8, payload, meta,
                                                     (float4*)F_out, mat_out, Jp_out, n);
    scan1_kernel<<<NG2/256, 256, 0, stream>>>(counts8, offs8, starts, bsum);
    scan2_kernel<<<1, 256, 0, stream>>>(bsum);
    scan3_kernel<<<NG2/256, 256, 0, stream>>>(starts, bsum, n);
    mover_kernel<<<blocks, 256, 0, stream>>>(payload, meta, starts, offs8, srec, n);
    gather_grid_kernel<<<(NG2*16)/256, 256, 0, stream>>>(srec, starts, gv);
    g2p_kernel<<<blocks, 256, 0, stream>>>(x, gv, x_out, v_out, C_out, n);
}